// Round 14
// baseline (1647.270 us; speedup 1.0000x reference)
//
#include <hip/hip_runtime.h>

// ---------------------------------------------------------------------------
// TrajectoryDecoder: B=4096, F=256, H=256, M=3, T=30 (T read from device)
// out = [trajectories (B,M,T,2) fp32][mode_probs (B,M) fp32]
// R13: R8 pass-split + unroll-1 (spill-free) + gx_ctx cached in 48 AGPRs.
// gx = ctx@w_ih0[:,2:] + biases is step-invariant; steady-state L0 now
// streams only w_hh0 (MFMA -25%, L2 bytes -25%, L0 LDS reads -50%).
// AGPR budget: acc peak 64 + gx 48 = 112; arch ~105 -> 217 < 256/wave.
// ---------------------------------------------------------------------------

typedef __attribute__((ext_vector_type(8))) short bf16x8;
typedef __attribute__((ext_vector_type(4))) float f32x4;
typedef __fp16 f16x2 __attribute__((ext_vector_type(2)));

__device__ __forceinline__ short f2bf(float f) {
    unsigned u = __builtin_bit_cast(unsigned, f);
    unsigned r = (u + 0x7fffu + ((u >> 16) & 1u)) >> 16;
    return (short)r;
}
__device__ __forceinline__ float bf2f(short s) {
    unsigned u = ((unsigned)(unsigned short)s) << 16;
    return __builtin_bit_cast(float, u);
}
__device__ __forceinline__ unsigned pk2(float a, float b) {
    return (unsigned)(unsigned short)f2bf(a) | ((unsigned)(unsigned short)f2bf(b) << 16);
}
__device__ __forceinline__ float unpk(unsigned u, int hi) {
    return __builtin_bit_cast(float, hi ? (u & 0xffff0000u) : (u << 16));
}
__device__ __forceinline__ unsigned pkh2(float a, float b) {
    f16x2 v = __builtin_amdgcn_cvt_pkrtz(a, b);
    return __builtin_bit_cast(unsigned, v);
}
__device__ __forceinline__ float uph(unsigned u, int hi) {
    f16x2 v = __builtin_bit_cast(f16x2, u);
    return (float)(hi ? v[1] : v[0]);
}
__device__ __forceinline__ float fast_sigmoid(float x) {
    x = fminf(fmaxf(x, -30.f), 30.f);
    float e = __builtin_amdgcn_exp2f(x * -1.442695041f);
    return __builtin_amdgcn_rcpf(1.f + e);
}
__device__ __forceinline__ float fast_tanh(float x) {
    x = fminf(fmaxf(x, -15.f), 15.f);
    float e = __builtin_amdgcn_exp2f(x * -2.885390082f);
    return (1.f - e) * __builtin_amdgcn_rcpf(1.f + e);
}
// AGPR storage for the step-invariant gx cache (spill-proof: AGPRs are
// otherwise idle between accumulator peaks in the split-pass structure).
__device__ __forceinline__ void aw(unsigned& dst, unsigned v) {
    asm volatile("v_accvgpr_write_b32 %0, %1" : "=a"(dst) : "v"(v));
}
__device__ __forceinline__ unsigned ar(unsigned a) {
    unsigned v;
    asm("v_accvgpr_read_b32 %0, %1" : "=v"(v) : "a"(a));
    return v;
}

// ---------------------------------------------------------------------------
// Weight prep: fp32 -> bf16, B-fragment consumption order.
// Regions (1KB blocks):
//   P0  [0,1152):    w_hh0 per (m,w8): 48 = [rz: ks*4+t (32)][n: 32+ks*2+nt]
//   P1  [1152,3456): per (m,w8): 96 = [rz: half*32+ks*4+t (64)]
//                                     [xn: 64+ks*2+nt][hn: 80+ks*2+nt]
//   PC  [3456,4608): w_ih0[:,2:258] per (m,w8): 48 = [ks*6+t6]
// ---------------------------------------------------------------------------
__global__ void prep_kernel(const float* __restrict__ w_ih0,
                            const float* __restrict__ w_hh0,
                            const float* __restrict__ w_ih1,
                            const float* __restrict__ w_hh1,
                            short* __restrict__ ws) {
    int bid = blockIdx.x;
    int L = threadIdx.x;
    const float* src;
    int srcRowLen, colBase, m, w, ks, t;
    if (bid < 1152) {
        int idx = bid, mw = idx / 48, blk = idx % 48;
        m = mw / 8; w = mw % 8;
        if (blk < 32) { ks = blk >> 2; t = blk & 3; }
        else { int q = blk - 32; ks = q >> 1; t = 4 + (q & 1); }
        src = w_hh0 + (size_t)m * 768 * 256; srcRowLen = 256; colBase = 0;
    } else if (bid < 3456) {
        int idx = bid - 1152, mw = idx / 96, blk = idx % 96;
        m = mw / 8; w = mw % 8;
        int half;
        if (blk < 64) { half = blk >> 5; ks = (blk >> 2) & 7; t = blk & 3; }
        else { int q = blk - 64; half = q >> 4; ks = (q >> 1) & 7; t = 4 + (q & 1); }
        src = (half ? w_hh1 : w_ih1) + (size_t)m * 768 * 256;
        srcRowLen = 256; colBase = 0;
    } else {
        int idx = bid - 3456, mw = idx / 48, blk = idx % 48;
        m = mw / 8; w = mw % 8; ks = blk / 6; t = blk % 6;
        src = w_ih0 + (size_t)m * 768 * 258; srcRowLen = 258; colBase = 2;
    }
    int row = (t >> 1) * 256 + 32 * w + (t & 1) * 16 + (L & 15);
    int col0 = colBase + ks * 32 + (L >> 4) * 8;
    short* dst = ws + (size_t)bid * 512 + L * 8;
    const float* s = src + (size_t)row * srcRowLen + col0;
#pragma unroll
    for (int j = 0; j < 8; ++j) dst[j] = f2bf(s[j]);
}

// ---------------------------------------------------------------------------
// Mode-probability MLP
// ---------------------------------------------------------------------------
__global__ __launch_bounds__(256) void modeprobs_kernel(
    const float* __restrict__ ctx, const float* __restrict__ w1,
    const float* __restrict__ b1, const float* __restrict__ w2,
    const float* __restrict__ b2, float* __restrict__ out,
    long probs_off) {
    __shared__ float w1s[64 * 256];
    int tid = threadIdx.x;
    int j = tid & 63;
    int rsub = tid >> 6;
#pragma unroll
    for (int i = 0; i < 64; ++i) w1s[tid + i * 256] = w1[tid + i * 256];
    float b1v = b1[j];
    float w2v0 = w2[j], w2v1 = w2[64 + j], w2v2 = w2[128 + j];
    float b20 = b2[0], b21 = b2[1], b22 = b2[2];
    __syncthreads();
    for (int c = 0; c < 16; ++c) {
        int brow = blockIdx.x * 64 + c * 4 + rsub;
        const float* crow = ctx + (size_t)brow * 256;
        float accv = b1v;
#pragma unroll 8
        for (int k = 0; k < 256; ++k) {
            int kk = (k + j) & 255;
            accv += w1s[j * 256 + kk] * crow[kk];
        }
        float h = fmaxf(accv, 0.f);
        float l0 = h * w2v0, l1 = h * w2v1, l2 = h * w2v2;
#pragma unroll
        for (int s = 1; s < 64; s <<= 1) {
            l0 += __shfl_xor(l0, s);
            l1 += __shfl_xor(l1, s);
            l2 += __shfl_xor(l2, s);
        }
        if (j == 0) {
            l0 += b20; l1 += b21; l2 += b22;
            float mx = fmaxf(l0, fmaxf(l1, l2));
            float e0 = __builtin_amdgcn_exp2f((l0 - mx) * 1.442695041f);
            float e1 = __builtin_amdgcn_exp2f((l1 - mx) * 1.442695041f);
            float e2 = __builtin_amdgcn_exp2f((l2 - mx) * 1.442695041f);
            float inv = 1.f / (e0 + e1 + e2);
            out[probs_off + (size_t)brow * 3 + 0] = e0 * inv;
            out[probs_off + (size_t)brow * 3 + 1] = e1 * inv;
            out[probs_off + (size_t)brow * 3 + 2] = e2 * inv;
        }
    }
}

// ---------------------------------------------------------------------------
// Persistent GRU decoder. Block = 64 batch rows x 1 mode; 512 threads
// (8 waves, wave w owns cols {32w..32w+32} per gate).
// ---------------------------------------------------------------------------
__global__ __launch_bounds__(512, 2) void decoder_kernel(
    const float* __restrict__ context,
    const float* __restrict__ w_ih0_f,   // (3,768,258): pos-weight cols 0..1
    const float* __restrict__ b_ih0, const float* __restrict__ b_hh0,
    const float* __restrict__ b_ih1, const float* __restrict__ b_hh1,
    const float* __restrict__ out_w, const float* __restrict__ out_b,
    const short* __restrict__ ws, float* __restrict__ out,
    const int* __restrict__ pT, int ntiles) {
    __shared__ short h0s[64 * 264];
    __shared__ short h1s[64 * 264];
    __shared__ float posD[128];
    __shared__ float owl[512];
    __shared__ float cwp0[768], cwp1[768];  // w_ih0[:,0], w_ih0[:,1]
    __shared__ float cbh0n[256];            // L0 n:  b_hh0
    __shared__ float cb1A[512];             // L1 rz: b_ih1+b_hh1
    __shared__ float cb1X[256];             // L1 n:  b_ih1
    __shared__ float cb1H[256];             // L1 n:  b_hh1

    const int bid = blockIdx.x;
    const int xcd = bid & 7, slot = bid >> 3;
    int mode, xl, nx;
    if (xcd < 3)      { mode = 0; xl = xcd;     nx = 3; }
    else if (xcd < 6) { mode = 1; xl = xcd - 3; nx = 3; }
    else              { mode = 2; xl = xcd - 6; nx = 2; }
    const int g = slot * nx + xl;
    if (g >= ntiles) return;
    const int m = mode;
    const int b0 = g * 64;

    const int T = *pT;
    const int tid = threadIdx.x;
    const int lane = tid & 63, w = tid >> 6;
    const int lr = lane & 15, quad = lane >> 4;

    if (tid < 128) posD[tid] = 0.f;
    owl[tid] = out_w[m * 512 + tid];
    if (tid < 512) cb1A[tid] = b_ih1[m * 768 + tid] + b_hh1[m * 768 + tid];
    if (tid < 256) {
        cbh0n[tid] = b_hh0[m * 768 + 512 + tid];
        cb1X[tid] = b_ih1[m * 768 + 512 + tid];
        cb1H[tid] = b_hh1[m * 768 + 512 + tid];
    }
    for (int c = tid; c < 768; c += 512) {
        cwp0[c] = w_ih0_f[((size_t)m * 768 + c) * 258 + 0];
        cwp1[c] = w_ih0_f[((size_t)m * 768 + c) * 258 + 1];
    }
#pragma unroll
    for (int i = 0; i < 32; ++i) {
        int idx = tid + i * 512;
        int r = idx >> 8, k = idx & 255;
        short v = f2bf(context[(size_t)(b0 + r) * 256 + k]);
        h0s[r * 264 + k] = v;
        h1s[r * 264 + k] = v;
    }
    const float ob0v = out_b[m * 2 + 0], ob1v = out_b[m * 2 + 1];

    const short* p0w = ws + ((size_t)(m * 8 + w) * 48) * 512 + lane * 8;
    const short* p1w = ws + (size_t)1152 * 512 + ((size_t)(m * 8 + w) * 96) * 512 + lane * 8;
    const short* pcw = ws + (size_t)3456 * 512 + ((size_t)(m * 8 + w) * 48) * 512 + lane * 8;

    const int cA = 32 * w + lr;        // n-tile 0 col (and rz tile base)
    const int cB = 32 * w + 16 + lr;   // n-tile 1 col

    __syncthreads();

    // ---- prologue: gx = ctx @ w_ih0[:,2:].T + b_ih0 (+b_hh0 on rz) -> AGPRs.
    //      h0s currently holds ctx, so read A-frags from it.
    unsigned gx[48];  // [(t6*4+rt)*2 + j] packed bf16 pairs, in AGPRs via aw()
    {
        f32x4 acc[6][4];
#pragma unroll
        for (int t6 = 0; t6 < 6; ++t6) {
            int c = (t6 >> 1) * 256 + 32 * w + (t6 & 1) * 16 + lr;
            float bi = b_ih0[m * 768 + c] + (t6 < 4 ? b_hh0[m * 768 + c] : 0.f);
#pragma unroll
            for (int rt = 0; rt < 4; ++rt) acc[t6][rt] = f32x4{bi, bi, bi, bi};
        }
        const short* bp = pcw;
#pragma unroll 1
        for (int ks = 0; ks < 8; ++ks) {
            bf16x8 a[4];
#pragma unroll
            for (int rt = 0; rt < 4; ++rt)
                a[rt] = *reinterpret_cast<const bf16x8*>(
                    h0s + (rt * 16 + lr) * 264 + ks * 32 + quad * 8);
#pragma unroll
            for (int t6 = 0; t6 < 6; ++t6) {
                bf16x8 b = *reinterpret_cast<const bf16x8*>(bp + t6 * 512);
#pragma unroll
                for (int rt = 0; rt < 4; ++rt)
                    acc[t6][rt] = __builtin_amdgcn_mfma_f32_16x16x32_bf16(
                        a[rt], b, acc[t6][rt], 0, 0, 0);
            }
            bp += 6 * 512;
        }
#pragma unroll
        for (int t6 = 0; t6 < 6; ++t6)
#pragma unroll
            for (int rt = 0; rt < 4; ++rt) {
                aw(gx[(t6 * 4 + rt) * 2 + 0], pk2(acc[t6][rt][0], acc[t6][rt][1]));
                aw(gx[(t6 * 4 + rt) * 2 + 1], pk2(acc[t6][rt][2], acc[t6][rt][3]));
            }
    }

    float cum0 = 0.f, cum1 = 0.f;

    for (int st = 0; st < T; ++st) {
        unsigned rp[2][4][2], zp[2][4][2];  // packed f16 gate values

        // ======== L0 pass A: r,z — init from gx, K-loop over h0 only ========
        {
            f32x4 arz[4][4];
#pragma unroll
            for (int rt = 0; rt < 4; ++rt)
#pragma unroll
                for (int r = 0; r < 4; ++r) {
                    int row = rt * 16 + quad * 4 + r;
                    float px = posD[row * 2], py = posD[row * 2 + 1];
#pragma unroll
                    for (int t = 0; t < 4; ++t) {
                        int c = (t >> 1) * 256 + ((t & 1) ? cB : cA);
                        arz[t][rt][r] =
                            unpk(ar(gx[(t * 4 + rt) * 2 + (r >> 1)]), r & 1) +
                            px * cwp0[c] + py * cwp1[c];
                    }
                }
            const short* bp0 = p0w;
#pragma unroll 1
            for (int ks = 0; ks < 8; ++ks) {
                bf16x8 ah[4];
#pragma unroll
                for (int rt = 0; rt < 4; ++rt)
                    ah[rt] = *reinterpret_cast<const bf16x8*>(
                        h0s + (rt * 16 + lr) * 264 + ks * 32 + quad * 8);
#pragma unroll
                for (int t = 0; t < 4; ++t) {
                    bf16x8 b = *reinterpret_cast<const bf16x8*>(bp0 + t * 512);
#pragma unroll
                    for (int rt = 0; rt < 4; ++rt)
                        arz[t][rt] = __builtin_amdgcn_mfma_f32_16x16x32_bf16(
                            ah[rt], b, arz[t][rt], 0, 0, 0);
                }
                bp0 += 4 * 512;
            }
#pragma unroll
            for (int nt = 0; nt < 2; ++nt)
#pragma unroll
                for (int rt = 0; rt < 4; ++rt) {
                    rp[nt][rt][0] = pkh2(fast_sigmoid(arz[nt][rt][0]),
                                         fast_sigmoid(arz[nt][rt][1]));
                    rp[nt][rt][1] = pkh2(fast_sigmoid(arz[nt][rt][2]),
                                         fast_sigmoid(arz[nt][rt][3]));
                    zp[nt][rt][0] = pkh2(fast_sigmoid(arz[2 + nt][rt][0]),
                                         fast_sigmoid(arz[2 + nt][rt][1]));
                    zp[nt][rt][1] = pkh2(fast_sigmoid(arz[2 + nt][rt][2]),
                                         fast_sigmoid(arz[2 + nt][rt][3]));
                }
        }
        // ======== L0 pass B: xn from gx; hn over h0 -> h0' ========
        {
            f32x4 ahn[2][4];
#pragma unroll
            for (int rt = 0; rt < 4; ++rt)
#pragma unroll
                for (int r = 0; r < 4; ++r)
#pragma unroll
                    for (int nt = 0; nt < 2; ++nt)
                        ahn[nt][rt][r] = cbh0n[nt ? cB : cA];
            const short* bp0 = p0w + 32 * 512;
#pragma unroll 1
            for (int ks = 0; ks < 8; ++ks) {
                bf16x8 ah[4];
#pragma unroll
                for (int rt = 0; rt < 4; ++rt)
                    ah[rt] = *reinterpret_cast<const bf16x8*>(
                        h0s + (rt * 16 + lr) * 264 + ks * 32 + quad * 8);
#pragma unroll
                for (int nt = 0; nt < 2; ++nt) {
                    bf16x8 b = *reinterpret_cast<const bf16x8*>(bp0 + nt * 512);
#pragma unroll
                    for (int rt = 0; rt < 4; ++rt)
                        ahn[nt][rt] = __builtin_amdgcn_mfma_f32_16x16x32_bf16(
                            ah[rt], b, ahn[nt][rt], 0, 0, 0);
                }
                bp0 += 2 * 512;
            }
            __syncthreads();  // B0: all h0 reads complete
#pragma unroll
            for (int nt = 0; nt < 2; ++nt) {
                int col = nt ? cB : cA;
#pragma unroll
                for (int rt = 0; rt < 4; ++rt)
#pragma unroll
                    for (int r = 0; r < 4; ++r) {
                        int row = rt * 16 + quad * 4 + r;
                        float px = posD[row * 2], py = posD[row * 2 + 1];
                        float rr = uph(rp[nt][rt][r >> 1], r & 1);
                        float zz = uph(zp[nt][rt][r >> 1], r & 1);
                        float xn =
                            unpk(ar(gx[((4 + nt) * 4 + rt) * 2 + (r >> 1)]), r & 1) +
                            px * cwp0[512 + col] + py * cwp1[512 + col];
                        float nn = fast_tanh(xn + rr * ahn[nt][rt][r]);
                        float hold = bf2f(h0s[row * 264 + col]);
                        h0s[row * 264 + col] = f2bf((1.f - zz) * nn + zz * hold);
                    }
            }
        }
        __syncthreads();  // B1: h0' visible

        // ======== L1 pass A: r,z over [h0'|h1] ========
        {
            f32x4 arz[4][4];
#pragma unroll
            for (int rt = 0; rt < 4; ++rt)
#pragma unroll
                for (int r = 0; r < 4; ++r)
#pragma unroll
                    for (int t = 0; t < 4; ++t) {
                        int c = (t >> 1) * 256 + ((t & 1) ? cB : cA);
                        arz[t][rt][r] = cb1A[c];
                    }
            const short* bq0 = p1w;            // w_ih1 rz (A = h0')
            const short* bq1 = p1w + 32 * 512; // w_hh1 rz (A = h1)
#pragma unroll 1
            for (int ks = 0; ks < 8; ++ks) {
                bf16x8 a0[4], a1[4];
#pragma unroll
                for (int rt = 0; rt < 4; ++rt) {
                    a0[rt] = *reinterpret_cast<const bf16x8*>(
                        h0s + (rt * 16 + lr) * 264 + ks * 32 + quad * 8);
                    a1[rt] = *reinterpret_cast<const bf16x8*>(
                        h1s + (rt * 16 + lr) * 264 + ks * 32 + quad * 8);
                }
#pragma unroll
                for (int t = 0; t < 4; ++t) {
                    bf16x8 b = *reinterpret_cast<const bf16x8*>(bq0 + t * 512);
#pragma unroll
                    for (int rt = 0; rt < 4; ++rt)
                        arz[t][rt] = __builtin_amdgcn_mfma_f32_16x16x32_bf16(
                            a0[rt], b, arz[t][rt], 0, 0, 0);
                }
#pragma unroll
                for (int t = 0; t < 4; ++t) {
                    bf16x8 b = *reinterpret_cast<const bf16x8*>(bq1 + t * 512);
#pragma unroll
                    for (int rt = 0; rt < 4; ++rt)
                        arz[t][rt] = __builtin_amdgcn_mfma_f32_16x16x32_bf16(
                            a1[rt], b, arz[t][rt], 0, 0, 0);
                }
                bq0 += 4 * 512;
                bq1 += 4 * 512;
            }
#pragma unroll
            for (int nt = 0; nt < 2; ++nt)
#pragma unroll
                for (int rt = 0; rt < 4; ++rt) {
                    rp[nt][rt][0] = pkh2(fast_sigmoid(arz[nt][rt][0]),
                                         fast_sigmoid(arz[nt][rt][1]));
                    rp[nt][rt][1] = pkh2(fast_sigmoid(arz[nt][rt][2]),
                                         fast_sigmoid(arz[nt][rt][3]));
                    zp[nt][rt][0] = pkh2(fast_sigmoid(arz[2 + nt][rt][0]),
                                         fast_sigmoid(arz[2 + nt][rt][1]));
                    zp[nt][rt][1] = pkh2(fast_sigmoid(arz[2 + nt][rt][2]),
                                         fast_sigmoid(arz[2 + nt][rt][3]));
                }
        }
        // ======== L1 pass B: xn (h0') + hn (h1) -> h1' ========
        {
            f32x4 axn[2][4], ahn[2][4];
#pragma unroll
            for (int rt = 0; rt < 4; ++rt)
#pragma unroll
                for (int r = 0; r < 4; ++r)
#pragma unroll
                    for (int nt = 0; nt < 2; ++nt) {
                        int cn = nt ? cB : cA;
                        axn[nt][rt][r] = cb1X[cn];
                        ahn[nt][rt][r] = cb1H[cn];
                    }
            const short* bx = p1w + 64 * 512;
            const short* bh = p1w + 80 * 512;
#pragma unroll 1
            for (int ks = 0; ks < 8; ++ks) {
                bf16x8 a0[4], a1[4];
#pragma unroll
                for (int rt = 0; rt < 4; ++rt) {
                    a0[rt] = *reinterpret_cast<const bf16x8*>(
                        h0s + (rt * 16 + lr) * 264 + ks * 32 + quad * 8);
                    a1[rt] = *reinterpret_cast<const bf16x8*>(
                        h1s + (rt * 16 + lr) * 264 + ks * 32 + quad * 8);
                }
#pragma unroll
                for (int nt = 0; nt < 2; ++nt) {
                    bf16x8 b = *reinterpret_cast<const bf16x8*>(bx + nt * 512);
#pragma unroll
                    for (int rt = 0; rt < 4; ++rt)
                        axn[nt][rt] = __builtin_amdgcn_mfma_f32_16x16x32_bf16(
                            a0[rt], b, axn[nt][rt], 0, 0, 0);
                }
#pragma unroll
                for (int nt = 0; nt < 2; ++nt) {
                    bf16x8 b = *reinterpret_cast<const bf16x8*>(bh + nt * 512);
#pragma unroll
                    for (int rt = 0; rt < 4; ++rt)
                        ahn[nt][rt] = __builtin_amdgcn_mfma_f32_16x16x32_bf16(
                            a1[rt], b, ahn[nt][rt], 0, 0, 0);
                }
                bx += 2 * 512;
                bh += 2 * 512;
            }
            __syncthreads();  // B2: all h1 reads complete
#pragma unroll
            for (int nt = 0; nt < 2; ++nt) {
                int col = nt ? cB : cA;
#pragma unroll
                for (int rt = 0; rt < 4; ++rt)
#pragma unroll
                    for (int r = 0; r < 4; ++r) {
                        int row = rt * 16 + quad * 4 + r;
                        float rr = uph(rp[nt][rt][r >> 1], r & 1);
                        float zz = uph(zp[nt][rt][r >> 1], r & 1);
                        float nn =
                            fast_tanh(axn[nt][rt][r] + rr * ahn[nt][rt][r]);
                        float hold = bf2f(h1s[row * 264 + col]);
                        h1s[row * 264 + col] = f2bf((1.f - zz) * nn + zz * hold);
                    }
            }
        }
        __syncthreads();  // B3: h1' visible

        // ---------------- delta = h1' @ ow.T + ob ; cumsum -> out
        {
            int brow = tid >> 3, p = tid & 7;
            float d0 = 0.f, d1 = 0.f;
#pragma unroll
            for (int j = 0; j < 4; ++j) {
                int cb = ((p + brow) & 7) * 8 + j * 64;
                bf16x8 hv8 = *reinterpret_cast<const bf16x8*>(h1s + brow * 264 + cb);
#pragma unroll
                for (int i = 0; i < 8; ++i) {
                    float hv = bf2f(hv8[i]);
                    d0 += hv * owl[cb + i];
                    d1 += hv * owl[256 + cb + i];
                }
            }
            d0 += __shfl_xor(d0, 1); d0 += __shfl_xor(d0, 2); d0 += __shfl_xor(d0, 4);
            d1 += __shfl_xor(d1, 1); d1 += __shfl_xor(d1, 2); d1 += __shfl_xor(d1, 4);
            d0 += ob0v;
            d1 += ob1v;
            if (p == 0) {
                cum0 += d0;
                cum1 += d1;
                size_t o = (((size_t)(b0 + brow) * 3 + m) * (size_t)T + st) * 2;
                out[o] = cum0;
                out[o + 1] = cum1;
                posD[brow * 2] = d0;
                posD[brow * 2 + 1] = d1;
            }
        }
        __syncthreads();  // B4: posD ready
    }
}

extern "C" void kernel_launch(void* const* d_in, const int* in_sizes, int n_in,
                              void* d_out, int out_size, void* d_ws, size_t ws_size,
                              hipStream_t stream) {
    const float* context = (const float*)d_in[0];
    const float* mp_w1 = (const float*)d_in[1];
    const float* mp_b1 = (const float*)d_in[2];
    const float* mp_w2 = (const float*)d_in[3];
    const float* mp_b2 = (const float*)d_in[4];
    const float* w_ih0 = (const float*)d_in[5];
    const float* w_hh0 = (const float*)d_in[6];
    const float* b_ih0 = (const float*)d_in[7];
    const float* b_hh0 = (const float*)d_in[8];
    const float* w_ih1 = (const float*)d_in[9];
    const float* w_hh1 = (const float*)d_in[10];
    const float* b_ih1 = (const float*)d_in[11];
    const float* b_hh1 = (const float*)d_in[12];
    const float* out_w = (const float*)d_in[13];
    const float* out_b = (const float*)d_in[14];
    const int* pT = (const int*)d_in[15];
    float* out = (float*)d_out;
    short* ws = (short*)d_ws;

    const int B = in_sizes[0] / 256;                      // 4096
    const int ntiles = B / 64;                            // 64
    const long probs_off = (long)out_size - (long)B * 3;

    prep_kernel<<<4608, 64, 0, stream>>>(w_ih0, w_hh0, w_ih1, w_hh1, ws);
    modeprobs_kernel<<<B / 64, 256, 0, stream>>>(context, mp_w1, mp_b1, mp_w2,
                                                 mp_b2, out, probs_off);
    const int nslots = (ntiles + 1) / 2;
    decoder_kernel<<<8 * nslots, 512, 0, stream>>>(
        context, w_ih0, b_ih0, b_hh0, b_ih1, b_hh1, out_w, out_b, ws, out, pT,
        ntiles);
}

// Round 15
// 959.233 us; speedup vs baseline: 1.7173x; 1.7173x over previous
//
#include <hip/hip_runtime.h>

// ---------------------------------------------------------------------------
// TrajectoryDecoder: B=4096, F=256, H=256, M=3, T=30 (T read from device)
// out = [trajectories (B,M,T,2) fp32][mode_probs (B,M) fp32]
// R14: revert to R9 (best measured: 928us decoder) + double-buffered h0
// (removes the L0 read/write barrier; 5 -> 4 barriers/step). gx caching is
// abandoned: R5/R11/R13 all proved any gx cache (AGPR or global) costs more
// in spills/latency than the 25% MFMA it saves. Spill-free discipline kept:
// merged rz+n (128 AGPR acc), #pragma unroll 1 K-loops, running pointers.
// ---------------------------------------------------------------------------

typedef __attribute__((ext_vector_type(8))) short bf16x8;
typedef __attribute__((ext_vector_type(4))) float f32x4;

__device__ __forceinline__ short f2bf(float f) {
    unsigned u = __builtin_bit_cast(unsigned, f);
    unsigned r = (u + 0x7fffu + ((u >> 16) & 1u)) >> 16;
    return (short)r;
}
__device__ __forceinline__ float bf2f(short s) {
    unsigned u = ((unsigned)(unsigned short)s) << 16;
    return __builtin_bit_cast(float, u);
}
__device__ __forceinline__ float fast_sigmoid(float x) {
    x = fminf(fmaxf(x, -30.f), 30.f);
    float e = __builtin_amdgcn_exp2f(x * -1.442695041f);
    return __builtin_amdgcn_rcpf(1.f + e);
}
__device__ __forceinline__ float fast_tanh(float x) {
    x = fminf(fmaxf(x, -15.f), 15.f);
    float e = __builtin_amdgcn_exp2f(x * -2.885390082f);
    return (1.f - e) * __builtin_amdgcn_rcpf(1.f + e);
}

// ---------------------------------------------------------------------------
// Weight prep: fp32 -> bf16, B-fragment consumption order.
// Regions (1KB blocks):
//   P0  [0,1152):    w_hh0 per (m,w8): 48 = [rz: ks*4+t (32)][n: 32+ks*2+nt]
//   P1  [1152,3456): per (m,w8): 96 = [rz: half*32+ks*4+t (64)]
//                                     [xn: 64+ks*2+nt][hn: 80+ks*2+nt]
//   PC  [3456,4608): w_ih0[:,2:258] per (m,w8): 48 = [ks*6+t6]
// ---------------------------------------------------------------------------
__global__ void prep_kernel(const float* __restrict__ w_ih0,
                            const float* __restrict__ w_hh0,
                            const float* __restrict__ w_ih1,
                            const float* __restrict__ w_hh1,
                            short* __restrict__ ws) {
    int bid = blockIdx.x;
    int L = threadIdx.x;
    const float* src;
    int srcRowLen, colBase, m, w, ks, t;
    if (bid < 1152) {
        int idx = bid, mw = idx / 48, blk = idx % 48;
        m = mw / 8; w = mw % 8;
        if (blk < 32) { ks = blk >> 2; t = blk & 3; }
        else { int q = blk - 32; ks = q >> 1; t = 4 + (q & 1); }
        src = w_hh0 + (size_t)m * 768 * 256; srcRowLen = 256; colBase = 0;
    } else if (bid < 3456) {
        int idx = bid - 1152, mw = idx / 96, blk = idx % 96;
        m = mw / 8; w = mw % 8;
        int half;
        if (blk < 64) { half = blk >> 5; ks = (blk >> 2) & 7; t = blk & 3; }
        else { int q = blk - 64; half = q >> 4; ks = (q >> 1) & 7; t = 4 + (q & 1); }
        src = (half ? w_hh1 : w_ih1) + (size_t)m * 768 * 256;
        srcRowLen = 256; colBase = 0;
    } else {
        int idx = bid - 3456, mw = idx / 48, blk = idx % 48;
        m = mw / 8; w = mw % 8; ks = blk / 6; t = blk % 6;
        src = w_ih0 + (size_t)m * 768 * 258; srcRowLen = 258; colBase = 2;
    }
    int row = (t >> 1) * 256 + 32 * w + (t & 1) * 16 + (L & 15);
    int col0 = colBase + ks * 32 + (L >> 4) * 8;
    short* dst = ws + (size_t)bid * 512 + L * 8;
    const float* s = src + (size_t)row * srcRowLen + col0;
#pragma unroll
    for (int j = 0; j < 8; ++j) dst[j] = f2bf(s[j]);
}

// ---------------------------------------------------------------------------
// Mode-probability MLP
// ---------------------------------------------------------------------------
__global__ __launch_bounds__(256) void modeprobs_kernel(
    const float* __restrict__ ctx, const float* __restrict__ w1,
    const float* __restrict__ b1, const float* __restrict__ w2,
    const float* __restrict__ b2, float* __restrict__ out,
    long probs_off) {
    __shared__ float w1s[64 * 256];
    int tid = threadIdx.x;
    int j = tid & 63;
    int rsub = tid >> 6;
#pragma unroll
    for (int i = 0; i < 64; ++i) w1s[tid + i * 256] = w1[tid + i * 256];
    float b1v = b1[j];
    float w2v0 = w2[j], w2v1 = w2[64 + j], w2v2 = w2[128 + j];
    float b20 = b2[0], b21 = b2[1], b22 = b2[2];
    __syncthreads();
    for (int c = 0; c < 16; ++c) {
        int brow = blockIdx.x * 64 + c * 4 + rsub;
        const float* crow = ctx + (size_t)brow * 256;
        float accv = b1v;
#pragma unroll 8
        for (int k = 0; k < 256; ++k) {
            int kk = (k + j) & 255;
            accv += w1s[j * 256 + kk] * crow[kk];
        }
        float h = fmaxf(accv, 0.f);
        float l0 = h * w2v0, l1 = h * w2v1, l2 = h * w2v2;
#pragma unroll
        for (int s = 1; s < 64; s <<= 1) {
            l0 += __shfl_xor(l0, s);
            l1 += __shfl_xor(l1, s);
            l2 += __shfl_xor(l2, s);
        }
        if (j == 0) {
            l0 += b20; l1 += b21; l2 += b22;
            float mx = fmaxf(l0, fmaxf(l1, l2));
            float e0 = __builtin_amdgcn_exp2f((l0 - mx) * 1.442695041f);
            float e1 = __builtin_amdgcn_exp2f((l1 - mx) * 1.442695041f);
            float e2 = __builtin_amdgcn_exp2f((l2 - mx) * 1.442695041f);
            float inv = 1.f / (e0 + e1 + e2);
            out[probs_off + (size_t)brow * 3 + 0] = e0 * inv;
            out[probs_off + (size_t)brow * 3 + 1] = e1 * inv;
            out[probs_off + (size_t)brow * 3 + 2] = e2 * inv;
        }
    }
}

// ---------------------------------------------------------------------------
// Persistent GRU decoder. Block = 64 batch rows x 1 mode; 512 threads
// (8 waves, wave w owns cols {32w..32w+32} per gate). h0 double-buffered.
// ---------------------------------------------------------------------------
__global__ __launch_bounds__(512, 2) void decoder_kernel(
    const float* __restrict__ context,
    const float* __restrict__ w_ih0_f,   // (3,768,258): pos-weight cols 0..1
    const float* __restrict__ b_ih0, const float* __restrict__ b_hh0,
    const float* __restrict__ b_ih1, const float* __restrict__ b_hh1,
    const float* __restrict__ out_w, const float* __restrict__ out_b,
    const short* __restrict__ ws, float* __restrict__ out,
    const int* __restrict__ pT, int ntiles) {
    __shared__ short ctxS[64 * 264];   // read-only after init
    __shared__ short h0a[64 * 264], h0b[64 * 264];  // double-buffered h0
    __shared__ short h1s[64 * 264];
    __shared__ float posD[128];
    __shared__ float owl[512];
    __shared__ float cwp0[768], cwp1[768];  // w_ih0[:,0], w_ih0[:,1]
    __shared__ float cbA[512];              // L0 rz: b_ih0+b_hh0
    __shared__ float cbXn[256];             // L0 n:  b_ih0
    __shared__ float cbh0n[256];            // L0 n:  b_hh0
    __shared__ float cb1A[512];             // L1 rz: b_ih1+b_hh1
    __shared__ float cb1X[256];             // L1 n:  b_ih1
    __shared__ float cb1H[256];             // L1 n:  b_hh1

    const int bid = blockIdx.x;
    const int xcd = bid & 7, slot = bid >> 3;
    int mode, xl, nx;
    if (xcd < 3)      { mode = 0; xl = xcd;     nx = 3; }
    else if (xcd < 6) { mode = 1; xl = xcd - 3; nx = 3; }
    else              { mode = 2; xl = xcd - 6; nx = 2; }
    const int g = slot * nx + xl;
    if (g >= ntiles) return;
    const int m = mode;
    const int b0 = g * 64;

    const int T = *pT;
    const int tid = threadIdx.x;
    const int lane = tid & 63, w = tid >> 6;
    const int lr = lane & 15, quad = lane >> 4;

    if (tid < 128) posD[tid] = 0.f;
    owl[tid] = out_w[m * 512 + tid];
    if (tid < 512) {
        cbA[tid] = b_ih0[m * 768 + tid] + b_hh0[m * 768 + tid];
        cb1A[tid] = b_ih1[m * 768 + tid] + b_hh1[m * 768 + tid];
    }
    if (tid < 256) {
        cbXn[tid] = b_ih0[m * 768 + 512 + tid];
        cbh0n[tid] = b_hh0[m * 768 + 512 + tid];
        cb1X[tid] = b_ih1[m * 768 + 512 + tid];
        cb1H[tid] = b_hh1[m * 768 + 512 + tid];
    }
    for (int c = tid; c < 768; c += 512) {
        cwp0[c] = w_ih0_f[((size_t)m * 768 + c) * 258 + 0];
        cwp1[c] = w_ih0_f[((size_t)m * 768 + c) * 258 + 1];
    }
#pragma unroll
    for (int i = 0; i < 32; ++i) {
        int idx = tid + i * 512;
        int r = idx >> 8, k = idx & 255;
        short v = f2bf(context[(size_t)(b0 + r) * 256 + k]);
        ctxS[r * 264 + k] = v;
        h0a[r * 264 + k] = v;
        h1s[r * 264 + k] = v;
    }
    const float ob0v = out_b[m * 2 + 0], ob1v = out_b[m * 2 + 1];

    const short* p0w = ws + ((size_t)(m * 8 + w) * 48) * 512 + lane * 8;
    const short* p1w = ws + (size_t)1152 * 512 + ((size_t)(m * 8 + w) * 96) * 512 + lane * 8;
    const short* pcw = ws + (size_t)3456 * 512 + ((size_t)(m * 8 + w) * 48) * 512 + lane * 8;

    const int cA = 32 * w + lr;        // n-tile 0 col (and rz tile base)
    const int cB = 32 * w + 16 + lr;   // n-tile 1 col

    __syncthreads();

    float cum0 = 0.f, cum1 = 0.f;

    for (int st = 0; st < T; ++st) {
        const short* h0c = (st & 1) ? h0b : h0a;   // current h0
        short* h0n_ = (st & 1) ? h0a : h0b;        // next h0 (no WAR hazard)

        // ======== layer 0 (merged rz+n, unroll-1 K-loop) ========
        {
            f32x4 arz[4][4], axn[2][4], ahn[2][4];
#pragma unroll
            for (int rt = 0; rt < 4; ++rt)
#pragma unroll
                for (int r = 0; r < 4; ++r) {
                    int row = rt * 16 + quad * 4 + r;
                    float px = posD[row * 2], py = posD[row * 2 + 1];
#pragma unroll
                    for (int t = 0; t < 4; ++t) {
                        int c = (t >> 1) * 256 + ((t & 1) ? cB : cA);
                        arz[t][rt][r] = cbA[c] + px * cwp0[c] + py * cwp1[c];
                    }
#pragma unroll
                    for (int nt = 0; nt < 2; ++nt) {
                        int cn = nt ? cB : cA;
                        axn[nt][rt][r] = cbXn[cn] + px * cwp0[512 + cn] +
                                         py * cwp1[512 + cn];
                        ahn[nt][rt][r] = cbh0n[cn];
                    }
                }
            const short* bpc = pcw;              // ctx weights: 6 tiles/ks
            const short* bp0rz = p0w;            // w_hh0 rz: 4 tiles/ks
            const short* bp0n = p0w + 32 * 512;  // w_hh0 n: 2 tiles/ks
#pragma unroll 1
            for (int ks = 0; ks < 8; ++ks) {
                bf16x8 ac[4], ah[4];
#pragma unroll
                for (int rt = 0; rt < 4; ++rt) {
                    ac[rt] = *reinterpret_cast<const bf16x8*>(
                        ctxS + (rt * 16 + lr) * 264 + ks * 32 + quad * 8);
                    ah[rt] = *reinterpret_cast<const bf16x8*>(
                        h0c + (rt * 16 + lr) * 264 + ks * 32 + quad * 8);
                }
#pragma unroll
                for (int t = 0; t < 4; ++t) {
                    bf16x8 b = *reinterpret_cast<const bf16x8*>(bpc + t * 512);
#pragma unroll
                    for (int rt = 0; rt < 4; ++rt)
                        arz[t][rt] = __builtin_amdgcn_mfma_f32_16x16x32_bf16(
                            ac[rt], b, arz[t][rt], 0, 0, 0);
                }
#pragma unroll
                for (int nt = 0; nt < 2; ++nt) {
                    bf16x8 b = *reinterpret_cast<const bf16x8*>(bpc + (4 + nt) * 512);
#pragma unroll
                    for (int rt = 0; rt < 4; ++rt)
                        axn[nt][rt] = __builtin_amdgcn_mfma_f32_16x16x32_bf16(
                            ac[rt], b, axn[nt][rt], 0, 0, 0);
                }
#pragma unroll
                for (int t = 0; t < 4; ++t) {
                    bf16x8 b = *reinterpret_cast<const bf16x8*>(bp0rz + t * 512);
#pragma unroll
                    for (int rt = 0; rt < 4; ++rt)
                        arz[t][rt] = __builtin_amdgcn_mfma_f32_16x16x32_bf16(
                            ah[rt], b, arz[t][rt], 0, 0, 0);
                }
#pragma unroll
                for (int nt = 0; nt < 2; ++nt) {
                    bf16x8 b = *reinterpret_cast<const bf16x8*>(bp0n + nt * 512);
#pragma unroll
                    for (int rt = 0; rt < 4; ++rt)
                        ahn[nt][rt] = __builtin_amdgcn_mfma_f32_16x16x32_bf16(
                            ah[rt], b, ahn[nt][rt], 0, 0, 0);
                }
                bpc += 6 * 512;
                bp0rz += 4 * 512;
                bp0n += 2 * 512;
            }
            // no barrier: epilogue writes h0n_ (other buffer), no WAR hazard
#pragma unroll
            for (int nt = 0; nt < 2; ++nt) {
                int col = nt ? cB : cA;
#pragma unroll
                for (int rt = 0; rt < 4; ++rt)
#pragma unroll
                    for (int r = 0; r < 4; ++r) {
                        int row = rt * 16 + quad * 4 + r;
                        float rr = fast_sigmoid(arz[nt][rt][r]);
                        float zz = fast_sigmoid(arz[2 + nt][rt][r]);
                        float nn =
                            fast_tanh(axn[nt][rt][r] + rr * ahn[nt][rt][r]);
                        float hold = bf2f(h0c[row * 264 + col]);
                        h0n_[row * 264 + col] = f2bf((1.f - zz) * nn + zz * hold);
                    }
            }
        }
        __syncthreads();  // B1: h0' visible

        // ======== layer 1 (merged rz+n, unroll-1 K-loop) ========
        {
            f32x4 arz[4][4], axn[2][4], ahn[2][4];
#pragma unroll
            for (int rt = 0; rt < 4; ++rt)
#pragma unroll
                for (int r = 0; r < 4; ++r) {
#pragma unroll
                    for (int t = 0; t < 4; ++t) {
                        int c = (t >> 1) * 256 + ((t & 1) ? cB : cA);
                        arz[t][rt][r] = cb1A[c];
                    }
#pragma unroll
                    for (int nt = 0; nt < 2; ++nt) {
                        int cn = nt ? cB : cA;
                        axn[nt][rt][r] = cb1X[cn];
                        ahn[nt][rt][r] = cb1H[cn];
                    }
                }
            const short* bq0 = p1w;            // w_ih1 rz (A = h0')
            const short* bq1 = p1w + 32 * 512; // w_hh1 rz (A = h1)
            const short* bx = p1w + 64 * 512;  // w_ih1 n  (A = h0')
            const short* bh = p1w + 80 * 512;  // w_hh1 n  (A = h1)
#pragma unroll 1
            for (int ks = 0; ks < 8; ++ks) {
                bf16x8 a0[4], a1[4];
#pragma unroll
                for (int rt = 0; rt < 4; ++rt) {
                    a0[rt] = *reinterpret_cast<const bf16x8*>(
                        h0n_ + (rt * 16 + lr) * 264 + ks * 32 + quad * 8);
                    a1[rt] = *reinterpret_cast<const bf16x8*>(
                        h1s + (rt * 16 + lr) * 264 + ks * 32 + quad * 8);
                }
#pragma unroll
                for (int t = 0; t < 4; ++t) {
                    bf16x8 b = *reinterpret_cast<const bf16x8*>(bq0 + t * 512);
#pragma unroll
                    for (int rt = 0; rt < 4; ++rt)
                        arz[t][rt] = __builtin_amdgcn_mfma_f32_16x16x32_bf16(
                            a0[rt], b, arz[t][rt], 0, 0, 0);
                }
#pragma unroll
                for (int nt = 0; nt < 2; ++nt) {
                    bf16x8 b = *reinterpret_cast<const bf16x8*>(bx + nt * 512);
#pragma unroll
                    for (int rt = 0; rt < 4; ++rt)
                        axn[nt][rt] = __builtin_amdgcn_mfma_f32_16x16x32_bf16(
                            a0[rt], b, axn[nt][rt], 0, 0, 0);
                }
#pragma unroll
                for (int t = 0; t < 4; ++t) {
                    bf16x8 b = *reinterpret_cast<const bf16x8*>(bq1 + t * 512);
#pragma unroll
                    for (int rt = 0; rt < 4; ++rt)
                        arz[t][rt] = __builtin_amdgcn_mfma_f32_16x16x32_bf16(
                            a1[rt], b, arz[t][rt], 0, 0, 0);
                }
#pragma unroll
                for (int nt = 0; nt < 2; ++nt) {
                    bf16x8 b = *reinterpret_cast<const bf16x8*>(bh + nt * 512);
#pragma unroll
                    for (int rt = 0; rt < 4; ++rt)
                        ahn[nt][rt] = __builtin_amdgcn_mfma_f32_16x16x32_bf16(
                            a1[rt], b, ahn[nt][rt], 0, 0, 0);
                }
                bq0 += 4 * 512;
                bq1 += 4 * 512;
                bx += 2 * 512;
                bh += 2 * 512;
            }
            __syncthreads();  // B2: all h1 reads complete
#pragma unroll
            for (int nt = 0; nt < 2; ++nt) {
                int col = nt ? cB : cA;
#pragma unroll
                for (int rt = 0; rt < 4; ++rt)
#pragma unroll
                    for (int r = 0; r < 4; ++r) {
                        int row = rt * 16 + quad * 4 + r;
                        float rr = fast_sigmoid(arz[nt][rt][r]);
                        float zz = fast_sigmoid(arz[2 + nt][rt][r]);
                        float nn =
                            fast_tanh(axn[nt][rt][r] + rr * ahn[nt][rt][r]);
                        float hold = bf2f(h1s[row * 264 + col]);
                        h1s[row * 264 + col] = f2bf((1.f - zz) * nn + zz * hold);
                    }
            }
        }
        __syncthreads();  // B3: h1' visible

        // ---------------- delta = h1' @ ow.T + ob ; cumsum -> out
        {
            int brow = tid >> 3, p = tid & 7;
            float d0 = 0.f, d1 = 0.f;
#pragma unroll
            for (int j = 0; j < 4; ++j) {
                int cb = ((p + brow) & 7) * 8 + j * 64;
                bf16x8 hv8 = *reinterpret_cast<const bf16x8*>(h1s + brow * 264 + cb);
#pragma unroll
                for (int i = 0; i < 8; ++i) {
                    float hv = bf2f(hv8[i]);
                    d0 += hv * owl[cb + i];
                    d1 += hv * owl[256 + cb + i];
                }
            }
            d0 += __shfl_xor(d0, 1); d0 += __shfl_xor(d0, 2); d0 += __shfl_xor(d0, 4);
            d1 += __shfl_xor(d1, 1); d1 += __shfl_xor(d1, 2); d1 += __shfl_xor(d1, 4);
            d0 += ob0v;
            d1 += ob1v;
            if (p == 0) {
                cum0 += d0;
                cum1 += d1;
                size_t o = (((size_t)(b0 + brow) * 3 + m) * (size_t)T + st) * 2;
                out[o] = cum0;
                out[o + 1] = cum1;
                posD[brow * 2] = d0;
                posD[brow * 2 + 1] = d1;
            }
        }
        __syncthreads();  // B4: posD ready
    }
}

extern "C" void kernel_launch(void* const* d_in, const int* in_sizes, int n_in,
                              void* d_out, int out_size, void* d_ws, size_t ws_size,
                              hipStream_t stream) {
    const float* context = (const float*)d_in[0];
    const float* mp_w1 = (const float*)d_in[1];
    const float* mp_b1 = (const float*)d_in[2];
    const float* mp_w2 = (const float*)d_in[3];
    const float* mp_b2 = (const float*)d_in[4];
    const float* w_ih0 = (const float*)d_in[5];
    const float* w_hh0 = (const float*)d_in[6];
    const float* b_ih0 = (const float*)d_in[7];
    const float* b_hh0 = (const float*)d_in[8];
    const float* w_ih1 = (const float*)d_in[9];
    const float* w_hh1 = (const float*)d_in[10];
    const float* b_ih1 = (const float*)d_in[11];
    const float* b_hh1 = (const float*)d_in[12];
    const float* out_w = (const float*)d_in[13];
    const float* out_b = (const float*)d_in[14];
    const int* pT = (const int*)d_in[15];
    float* out = (float*)d_out;
    short* ws = (short*)d_ws;

    const int B = in_sizes[0] / 256;                      // 4096
    const int ntiles = B / 64;                            // 64
    const long probs_off = (long)out_size - (long)B * 3;

    prep_kernel<<<4608, 64, 0, stream>>>(w_ih0, w_hh0, w_ih1, w_hh1, ws);
    modeprobs_kernel<<<B / 64, 256, 0, stream>>>(context, mp_w1, mp_b1, mp_w2,
                                                 mp_b2, out, probs_off);
    const int nslots = (ntiles + 1) / 2;
    decoder_kernel<<<8 * nslots, 512, 0, stream>>>(
        context, w_ih0, b_ih0, b_hh0, b_ih1, b_hh1, out_w, out_b, ws, out, pT,
        ntiles);
}